// Round 5
// baseline (5530.962 us; speedup 1.0000x reference)
//
#include <hip/hip_runtime.h>

// EdgeFeature kNN (DGCNN): B=4, D=64, N=4096, K=16, fp32 in/out.
// Ranking replicates the numpy fp32 reference pipeline bit-exactly:
//   sq_n  = numpy pairwise_sum (8-accumulator unroll) of fl(x_d^2)
//   dot   = sequential over d of  a = fmaf(x_d, y_d, a)   (einsum axpy w/ FMA)
//   d2    = fl(fl(sq_n + sq_m) - fl(2*dot));  dist = fl(sqrt(max(d2,0)))
//   order = (dist_f32, index) lexicographic (stable top_k tie-break)
// Key pack: (dist_bits << 32) | m  -> one u64 compare == lex order.
// R5: __launch_bounds__(256,4) caps VGPR<=128 (was 224 -> 2 waves/SIMD);
//     NCHUNK 8->16 doubles grid to 1024 blocks (4/CU). Occupancy was 11.8%.

#define BATCH 4
#define DIMS 64
#define NPTS 4096
#define KNN 16
#define NCHUNK 16
#define CHLEN 256      // NPTS / NCHUNK
#define MTILE 128
#define XTPAD 68       // float stride for transposed LDS tile (16B-aligned)

typedef unsigned long long u64;
typedef unsigned int u32;

// ---- kernel 0: per-point squared norm, numpy pairwise_sum order ---------
__global__ __launch_bounds__(256) void ef_sq_kernel(const float* __restrict__ pc,
                                                    float* __restrict__ sq) {
    int gid = blockIdx.x * 256 + threadIdx.x;     // b*NPTS + n
    int b = gid >> 12;
    int n = gid & (NPTS - 1);
    const float* p = pc + (size_t)b * DIMS * NPTS + n;
    float r[8];
#pragma unroll
    for (int j = 0; j < 8; ++j) {
        float v = p[(size_t)j * NPTS];
        r[j] = __fmul_rn(v, v);
    }
#pragma unroll
    for (int i = 8; i < DIMS; i += 8) {
#pragma unroll
        for (int j = 0; j < 8; ++j) {
            float v = p[(size_t)(i + j) * NPTS];
            r[j] = __fadd_rn(r[j], __fmul_rn(v, v));
        }
    }
    float t01 = __fadd_rn(r[0], r[1]);
    float t23 = __fadd_rn(r[2], r[3]);
    float t45 = __fadd_rn(r[4], r[5]);
    float t67 = __fadd_rn(r[6], r[7]);
    sq[gid] = __fadd_rn(__fadd_rn(t01, t23), __fadd_rn(t45, t67));
}

// ---- kernel 1: per-(row, chunk) partial top-16 --------------------------
__global__ __launch_bounds__(256, 4) void ef_knn_partial(const float* __restrict__ pc,
                                                         const float* __restrict__ sq,
                                                         u64* __restrict__ pKey) {
    __shared__ __align__(16) float smXT[MTILE][XTPAD]; // [mt][d], transposed tile
    __shared__ float smSq[MTILE];

    int tid = threadIdx.x;
    int n = blockIdx.x * 256 + tid;
    int c = blockIdx.y;
    int b = blockIdx.z;
    const float* pcb = pc + (size_t)b * DIMS * NPTS;

    float xr[DIMS];
#pragma unroll
    for (int d = 0; d < DIMS; ++d) xr[d] = pcb[(size_t)d * NPTS + n];
    float sqn = sq[b * NPTS + n];

    u64 key[KNN];
#pragma unroll
    for (int j = 0; j < KNN; ++j) key[j] = ~0ULL;

    int m0c = c * CHLEN;
    for (int t = 0; t < CHLEN / MTILE; ++t) {
        int m0 = m0c + t * MTILE;
        __syncthreads();
#pragma unroll
        for (int i = 0; i < (DIMS * MTILE) / 256; ++i) {  // 32 staging stores
            int off = i * 256 + tid;
            int d = off >> 7;              // MTILE = 128
            int mt = off & (MTILE - 1);
            smXT[mt][d] = pcb[(size_t)d * NPTS + (m0 + mt)];
        }
        if (tid < MTILE) smSq[tid] = sq[b * NPTS + m0 + tid];
        __syncthreads();

        for (int mt = 0; mt < MTILE; mt += 4) {
            const float4* p0 = (const float4*)(&smXT[mt + 0][0]);
            const float4* p1 = (const float4*)(&smXT[mt + 1][0]);
            const float4* p2 = (const float4*)(&smXT[mt + 2][0]);
            const float4* p3 = (const float4*)(&smXT[mt + 3][0]);
            // 4 independent candidates; each accumulator strictly sequential in d.
            float a0 = 0.f, a1 = 0.f, a2 = 0.f, a3 = 0.f;
#pragma unroll
            for (int q = 0; q < 16; ++q) {
                float4 v0 = p0[q], v1 = p1[q], v2 = p2[q], v3 = p3[q];
                float x0 = xr[4 * q + 0], x1 = xr[4 * q + 1];
                float x2 = xr[4 * q + 2], x3 = xr[4 * q + 3];
                a0 = fmaf(x0, v0.x, a0); a0 = fmaf(x1, v0.y, a0);
                a0 = fmaf(x2, v0.z, a0); a0 = fmaf(x3, v0.w, a0);
                a1 = fmaf(x0, v1.x, a1); a1 = fmaf(x1, v1.y, a1);
                a1 = fmaf(x2, v1.z, a1); a1 = fmaf(x3, v1.w, a1);
                a2 = fmaf(x0, v2.x, a2); a2 = fmaf(x1, v2.y, a2);
                a2 = fmaf(x2, v2.z, a2); a2 = fmaf(x3, v2.w, a2);
                a3 = fmaf(x0, v3.x, a3); a3 = fmaf(x1, v3.y, a3);
                a3 = fmaf(x2, v3.z, a3); a3 = fmaf(x3, v3.w, a3);
            }
            float dots[4] = {a0, a1, a2, a3};
#pragma unroll
            for (int i = 0; i < 4; ++i) {
                int m = m0 + mt + i;
                float t1 = __fadd_rn(sqn, smSq[mt + i]);
                float d2 = __fsub_rn(t1, __fmul_rn(2.0f, dots[i]));
                float dist = __fsqrt_rn(fmaxf(d2, 0.f));
                u64 cand = ((u64)__float_as_uint(dist) << 32) | (u64)(u32)m;
                if ((m != n) && (cand < key[KNN - 1])) {
                    bool placed = false;
#pragma unroll
                    for (int j = KNN - 1; j >= 1; --j) {
                        if (!placed) {
                            if (cand < key[j - 1]) {
                                key[j] = key[j - 1];
                            } else {
                                key[j] = cand;
                                placed = true;
                            }
                        }
                    }
                    if (!placed) key[0] = cand;
                }
            }
        }
    }

    u64* dst = pKey + ((size_t)(b * NPTS + n) * NCHUNK + c) * KNN;
#pragma unroll
    for (int j = 0; j < KNN; ++j) dst[j] = key[j];
}

// ---- kernel 2: merge 16 sorted partial lists per row, emit idx as float -
__global__ __launch_bounds__(256) void ef_knn_merge(const u64* __restrict__ pKey,
                                                    float* __restrict__ outIdxF) {
    int r = blockIdx.x * 256 + threadIdx.x;       // b*NPTS + n, 16384 rows
    const u64* src = pKey + (size_t)r * (NCHUNK * KNN);
    u64 key[KNN];
#pragma unroll
    for (int j = 0; j < KNN; ++j) key[j] = src[j];   // chunk 0 is sorted
    for (int c = 1; c < NCHUNK; ++c) {
#pragma unroll
        for (int j = 0; j < KNN; ++j) {
            u64 cand = src[c * KNN + j];
            if (cand < key[KNN - 1]) {
                bool placed = false;
#pragma unroll
                for (int p = KNN - 1; p >= 1; --p) {
                    if (!placed) {
                        if (cand < key[p - 1]) {
                            key[p] = key[p - 1];
                        } else {
                            key[p] = cand;
                            placed = true;
                        }
                    }
                }
                if (!placed) key[0] = cand;
            }
        }
    }
#pragma unroll
    for (int j = 0; j < KNN; ++j)
        outIdxF[(size_t)r * KNN + j] = (float)(u32)(key[j] & 0xFFFFFFFFu);
}

// ---- kernel 3: edge features -------------------------------------------
// out[b][ch][n][k]: ch<64 -> central, ch>=64 -> neighbor - central.
__global__ __launch_bounds__(256) void ef_edge_kernel(const float* __restrict__ pc,
                                                      const float* __restrict__ idxF,
                                                      float* __restrict__ out) {
    int gid = blockIdx.x * 256 + threadIdx.x;      // B*N*K = 262144
    int b = gid >> 16;                             // N*K = 65536
    int nk = gid & 65535;
    int n = nk >> 4;
    int m = (int)idxF[gid];
    const float* pcb = pc + (size_t)b * DIMS * NPTS;
    float* ob = out + (size_t)b * 2 * DIMS * NPTS * KNN;
#pragma unroll
    for (int d = 0; d < DIMS; ++d) {
        float cv = pcb[(size_t)d * NPTS + n];
        float nv = pcb[(size_t)d * NPTS + m];
        ob[(size_t)d * (NPTS * KNN) + nk] = cv;
        ob[(size_t)(DIMS + d) * (NPTS * KNN) + nk] = nv - cv;
    }
}

extern "C" void kernel_launch(void* const* d_in, const int* in_sizes, int n_in,
                              void* d_out, int out_size, void* d_ws, size_t ws_size,
                              hipStream_t stream) {
    const float* pc = (const float*)d_in[0];
    float* out = (float*)d_out;

    // Scratch lives inside the edge-feature region of d_out (fully overwritten
    // by ef_edge_kernel at the end): 33.5 MB of partial keys + 64 KB of sq.
    u64* pKey = (u64*)d_out;                          // [B*N][NCHUNK][KNN] u64 = 33.5 MB
    float* sq = out + 8388608;                        // after the 33.5 MB key block
    float* outIdxF = out + (size_t)BATCH * 2 * DIMS * NPTS * KNN; // 33,554,432

    ef_sq_kernel<<<(BATCH * NPTS) / 256, 256, 0, stream>>>(pc, sq);
    ef_knn_partial<<<dim3(NPTS / 256, NCHUNK, BATCH), 256, 0, stream>>>(pc, sq, pKey);
    ef_knn_merge<<<(BATCH * NPTS) / 256, 256, 0, stream>>>(pKey, outIdxF);
    ef_edge_kernel<<<(BATCH * NPTS * KNN) / 256, 256, 0, stream>>>(pc, outIdxF, out);
}

// Round 6
// 1966.652 us; speedup vs baseline: 2.8124x; 2.8124x over previous
//
#include <hip/hip_runtime.h>

// EdgeFeature kNN (DGCNN): B=4, D=64, N=4096, K=16, fp32 in/out.
// Ranking replicates the numpy fp32 reference pipeline bit-exactly:
//   sq_n  = numpy pairwise_sum (8-accumulator unroll) of fl(x_d^2)
//   dot   = sequential over d of  a = fmaf(x_d, y_d, a)   (einsum axpy w/ FMA)
//   d2    = fl(fl(sq_n + sq_m) - fl(2*dot));  dist = fl(sqrt(max(d2,0)))
//   order = (dist_f32, index) lexicographic (stable top_k tie-break)
// Key pack: (dist_bits << 32) | m  -> one u64 compare == lex order.
// R6: round-5's (256,4) cap forced VGPR 224->64 + 8 GB spill traffic (5.3 ms).
//     Now: 2-wide candidate unroll (smaller live set) + (256,3) cap (~170).
//     Tripwire: FETCH_SIZE must stay ~17 MB; if it balloons, the cap spilled.

#define BATCH 4
#define DIMS 64
#define NPTS 4096
#define KNN 16
#define NCHUNK 16
#define CHLEN 256      // NPTS / NCHUNK
#define MTILE 128
#define XTPAD 68       // float stride for transposed LDS tile (16B-aligned)

typedef unsigned long long u64;
typedef unsigned int u32;

// ---- kernel 0: per-point squared norm, numpy pairwise_sum order ---------
__global__ __launch_bounds__(256) void ef_sq_kernel(const float* __restrict__ pc,
                                                    float* __restrict__ sq) {
    int gid = blockIdx.x * 256 + threadIdx.x;     // b*NPTS + n
    int b = gid >> 12;
    int n = gid & (NPTS - 1);
    const float* p = pc + (size_t)b * DIMS * NPTS + n;
    float r[8];
#pragma unroll
    for (int j = 0; j < 8; ++j) {
        float v = p[(size_t)j * NPTS];
        r[j] = __fmul_rn(v, v);
    }
#pragma unroll
    for (int i = 8; i < DIMS; i += 8) {
#pragma unroll
        for (int j = 0; j < 8; ++j) {
            float v = p[(size_t)(i + j) * NPTS];
            r[j] = __fadd_rn(r[j], __fmul_rn(v, v));
        }
    }
    float t01 = __fadd_rn(r[0], r[1]);
    float t23 = __fadd_rn(r[2], r[3]);
    float t45 = __fadd_rn(r[4], r[5]);
    float t67 = __fadd_rn(r[6], r[7]);
    sq[gid] = __fadd_rn(__fadd_rn(t01, t23), __fadd_rn(t45, t67));
}

// ---- kernel 1: per-(row, chunk) partial top-16 --------------------------
__global__ __launch_bounds__(256, 3) void ef_knn_partial(const float* __restrict__ pc,
                                                         const float* __restrict__ sq,
                                                         u64* __restrict__ pKey) {
    __shared__ __align__(16) float smXT[MTILE][XTPAD]; // [mt][d], transposed tile
    __shared__ float smSq[MTILE];

    int tid = threadIdx.x;
    int n = blockIdx.x * 256 + tid;
    int c = blockIdx.y;
    int b = blockIdx.z;
    const float* pcb = pc + (size_t)b * DIMS * NPTS;

    float xr[DIMS];
#pragma unroll
    for (int d = 0; d < DIMS; ++d) xr[d] = pcb[(size_t)d * NPTS + n];
    float sqn = sq[b * NPTS + n];

    u64 key[KNN];
#pragma unroll
    for (int j = 0; j < KNN; ++j) key[j] = ~0ULL;

    int m0c = c * CHLEN;
    for (int t = 0; t < CHLEN / MTILE; ++t) {
        int m0 = m0c + t * MTILE;
        __syncthreads();
#pragma unroll
        for (int i = 0; i < (DIMS * MTILE) / 256; ++i) {  // 32 staging stores
            int off = i * 256 + tid;
            int d = off >> 7;              // MTILE = 128
            int mt = off & (MTILE - 1);
            smXT[mt][d] = pcb[(size_t)d * NPTS + (m0 + mt)];
        }
        if (tid < MTILE) smSq[tid] = sq[b * NPTS + m0 + tid];
        __syncthreads();

        for (int mt = 0; mt < MTILE; mt += 2) {
            const float4* p0 = (const float4*)(&smXT[mt + 0][0]);
            const float4* p1 = (const float4*)(&smXT[mt + 1][0]);
            // 2 independent candidates; each accumulator strictly sequential in d.
            float a0 = 0.f, a1 = 0.f;
#pragma unroll
            for (int q = 0; q < 16; ++q) {
                float4 v0 = p0[q], v1 = p1[q];
                float x0 = xr[4 * q + 0], x1 = xr[4 * q + 1];
                float x2 = xr[4 * q + 2], x3 = xr[4 * q + 3];
                a0 = fmaf(x0, v0.x, a0); a0 = fmaf(x1, v0.y, a0);
                a0 = fmaf(x2, v0.z, a0); a0 = fmaf(x3, v0.w, a0);
                a1 = fmaf(x0, v1.x, a1); a1 = fmaf(x1, v1.y, a1);
                a1 = fmaf(x2, v1.z, a1); a1 = fmaf(x3, v1.w, a1);
            }
            float dots[2] = {a0, a1};
#pragma unroll
            for (int i = 0; i < 2; ++i) {
                int m = m0 + mt + i;
                float t1 = __fadd_rn(sqn, smSq[mt + i]);
                float d2 = __fsub_rn(t1, __fmul_rn(2.0f, dots[i]));
                float dist = __fsqrt_rn(fmaxf(d2, 0.f));
                u64 cand = ((u64)__float_as_uint(dist) << 32) | (u64)(u32)m;
                if ((m != n) && (cand < key[KNN - 1])) {
                    bool placed = false;
#pragma unroll
                    for (int j = KNN - 1; j >= 1; --j) {
                        if (!placed) {
                            if (cand < key[j - 1]) {
                                key[j] = key[j - 1];
                            } else {
                                key[j] = cand;
                                placed = true;
                            }
                        }
                    }
                    if (!placed) key[0] = cand;
                }
            }
        }
    }

    u64* dst = pKey + ((size_t)(b * NPTS + n) * NCHUNK + c) * KNN;
#pragma unroll
    for (int j = 0; j < KNN; ++j) dst[j] = key[j];
}

// ---- kernel 2: merge 16 sorted partial lists per row, emit idx as float -
__global__ __launch_bounds__(256) void ef_knn_merge(const u64* __restrict__ pKey,
                                                    float* __restrict__ outIdxF) {
    int r = blockIdx.x * 256 + threadIdx.x;       // b*NPTS + n, 16384 rows
    const u64* src = pKey + (size_t)r * (NCHUNK * KNN);
    u64 key[KNN];
#pragma unroll
    for (int j = 0; j < KNN; ++j) key[j] = src[j];   // chunk 0 is sorted
    for (int c = 1; c < NCHUNK; ++c) {
#pragma unroll
        for (int j = 0; j < KNN; ++j) {
            u64 cand = src[c * KNN + j];
            if (cand < key[KNN - 1]) {
                bool placed = false;
#pragma unroll
                for (int p = KNN - 1; p >= 1; --p) {
                    if (!placed) {
                        if (cand < key[p - 1]) {
                            key[p] = key[p - 1];
                        } else {
                            key[p] = cand;
                            placed = true;
                        }
                    }
                }
                if (!placed) key[0] = cand;
            }
        }
    }
#pragma unroll
    for (int j = 0; j < KNN; ++j)
        outIdxF[(size_t)r * KNN + j] = (float)(u32)(key[j] & 0xFFFFFFFFu);
}

// ---- kernel 3: edge features -------------------------------------------
// out[b][ch][n][k]: ch<64 -> central, ch>=64 -> neighbor - central.
__global__ __launch_bounds__(256) void ef_edge_kernel(const float* __restrict__ pc,
                                                      const float* __restrict__ idxF,
                                                      float* __restrict__ out) {
    int gid = blockIdx.x * 256 + threadIdx.x;      // B*N*K = 262144
    int b = gid >> 16;                             // N*K = 65536
    int nk = gid & 65535;
    int n = nk >> 4;
    int m = (int)idxF[gid];
    const float* pcb = pc + (size_t)b * DIMS * NPTS;
    float* ob = out + (size_t)b * 2 * DIMS * NPTS * KNN;
#pragma unroll
    for (int d = 0; d < DIMS; ++d) {
        float cv = pcb[(size_t)d * NPTS + n];
        float nv = pcb[(size_t)d * NPTS + m];
        ob[(size_t)d * (NPTS * KNN) + nk] = cv;
        ob[(size_t)(DIMS + d) * (NPTS * KNN) + nk] = nv - cv;
    }
}

extern "C" void kernel_launch(void* const* d_in, const int* in_sizes, int n_in,
                              void* d_out, int out_size, void* d_ws, size_t ws_size,
                              hipStream_t stream) {
    const float* pc = (const float*)d_in[0];
    float* out = (float*)d_out;

    // Scratch lives inside the edge-feature region of d_out (fully overwritten
    // by ef_edge_kernel at the end): 33.5 MB of partial keys + 64 KB of sq.
    u64* pKey = (u64*)d_out;                          // [B*N][NCHUNK][KNN] u64 = 33.5 MB
    float* sq = out + 8388608;                        // after the 33.5 MB key block
    float* outIdxF = out + (size_t)BATCH * 2 * DIMS * NPTS * KNN; // 33,554,432

    ef_sq_kernel<<<(BATCH * NPTS) / 256, 256, 0, stream>>>(pc, sq);
    ef_knn_partial<<<dim3(NPTS / 256, NCHUNK, BATCH), 256, 0, stream>>>(pc, sq, pKey);
    ef_knn_merge<<<(BATCH * NPTS) / 256, 256, 0, stream>>>(pKey, outIdxF);
    ef_edge_kernel<<<(BATCH * NPTS * KNN) / 256, 256, 0, stream>>>(pc, outIdxF, out);
}

// Round 7
// 821.662 us; speedup vs baseline: 6.7314x; 2.3935x over previous
//
#include <hip/hip_runtime.h>

// EdgeFeature kNN (DGCNN): B=4, D=64, N=4096, K=16, fp32 in/out.
// Ranking replicates the numpy fp32 reference pipeline bit-exactly:
//   sq_n  = numpy pairwise_sum (8-accumulator unroll) of fl(x_d^2)
//   dot   = sequential over d of  a = fmaf(x_d, y_d, a)   (einsum axpy w/ FMA)
//   d2    = fl(fl(sq_n + sq_m) - fl(2*dot));  dist = fl(sqrt(max(d2,0)))
//   order = (dist_f32, index) lexicographic (stable top_k tie-break)
// Key pack: (dist_bits << 32) | m  -> one u64 compare == lex order.
//
// R7: launch_bounds caps spill catastrophically on gfx950 (R5: 8GB, R6: 5.7GB
//     scratch traffic) -- removed. New structure: candidate rows are
//     wave-uniform, so read them via the SCALAR path (s_load) from a
//     pre-transposed pcT[b][m][d], eliminating the LDS broadcast writeback
//     (1 KB regwrites / b128) that bottlenecked R4 at VALUBusy=36%.
//     No LDS, no barriers in the hot kernel; VGPR ~116 -> 4 waves/SIMD.

#define BATCH 4
#define DIMS 64
#define NPTS 4096
#define KNN 16
#define NCHUNK 16
#define CHLEN 256      // NPTS / NCHUNK

typedef unsigned long long u64;
typedef unsigned int u32;

// ---- kernel 0: per-point squared norm, numpy pairwise_sum order ---------
__global__ __launch_bounds__(256) void ef_sq_kernel(const float* __restrict__ pc,
                                                    float* __restrict__ sq) {
    int gid = blockIdx.x * 256 + threadIdx.x;     // b*NPTS + n
    int b = gid >> 12;
    int n = gid & (NPTS - 1);
    const float* p = pc + (size_t)b * DIMS * NPTS + n;
    float r[8];
#pragma unroll
    for (int j = 0; j < 8; ++j) {
        float v = p[(size_t)j * NPTS];
        r[j] = __fmul_rn(v, v);
    }
#pragma unroll
    for (int i = 8; i < DIMS; i += 8) {
#pragma unroll
        for (int j = 0; j < 8; ++j) {
            float v = p[(size_t)(i + j) * NPTS];
            r[j] = __fadd_rn(r[j], __fmul_rn(v, v));
        }
    }
    float t01 = __fadd_rn(r[0], r[1]);
    float t23 = __fadd_rn(r[2], r[3]);
    float t45 = __fadd_rn(r[4], r[5]);
    float t67 = __fadd_rn(r[6], r[7]);
    sq[gid] = __fadd_rn(__fadd_rn(t01, t23), __fadd_rn(t45, t67));
}

// ---- kernel 0b: transpose pc[b][d][m] -> pcT[(b*N+m)*64+d] --------------
__global__ __launch_bounds__(256) void ef_transpose(const float* __restrict__ pc,
                                                    float* __restrict__ pcT) {
    __shared__ float smT[DIMS][65];               // 65: conflict-free both phases
    int tid = threadIdx.x;
    int m0 = blockIdx.x * 64;
    int b = blockIdx.y;
    const float* pcb = pc + (size_t)b * DIMS * NPTS;
#pragma unroll
    for (int i = 0; i < 16; ++i) {                // load: coalesced over m
        int idx = i * 256 + tid;
        int d = idx >> 6;
        int m = idx & 63;
        smT[d][m] = pcb[(size_t)d * NPTS + m0 + m];
    }
    __syncthreads();
#pragma unroll
    for (int i = 0; i < 16; ++i) {                // store: coalesced over d
        int idx = i * 256 + tid;
        int m = idx >> 6;
        int d = idx & 63;
        pcT[((size_t)b * NPTS + m0 + m) * DIMS + d] = smT[d][m];
    }
}

// ---- kernel 1: per-(row, chunk) partial top-16 --------------------------
// Candidate rows come from pcT via wave-uniform (scalar) loads; query row
// xr[] and keys live in VGPRs. No LDS, no barriers.
__global__ __launch_bounds__(256) void ef_knn_partial(const float* __restrict__ pcT,
                                                      const float* __restrict__ sq,
                                                      u64* __restrict__ pKey) {
    int tid = threadIdx.x;
    int r = blockIdx.x * 256 + tid;               // global row: b*NPTS + n
    int c = blockIdx.y;
    int b = r >> 12;
    int n = r & (NPTS - 1);

    // per-lane query row: contiguous 256 B from pcT
    const float* xrp = pcT + (size_t)r * DIMS;
    float xr[DIMS];
#pragma unroll
    for (int q = 0; q < DIMS / 4; ++q) {
        float4 v = ((const float4*)xrp)[q];
        xr[4 * q + 0] = v.x; xr[4 * q + 1] = v.y;
        xr[4 * q + 2] = v.z; xr[4 * q + 3] = v.w;
    }
    float sqn = sq[r];

    u64 key[KNN];
#pragma unroll
    for (int j = 0; j < KNN; ++j) key[j] = ~0ULL;

    int m0 = c * CHLEN;
    const float* cb = pcT + ((size_t)b * NPTS + m0) * DIMS;   // wave-uniform base
    const float* sqb = sq + b * NPTS + m0;

    for (int mi = 0; mi < CHLEN; ++mi) {
        const float* crow = cb + (size_t)mi * DIMS;           // uniform address
        float a = 0.f;
#pragma unroll
        for (int d = 0; d < DIMS; ++d) {
            a = fmaf(xr[d], crow[d], a);          // scalar-load candidate operand
        }
        float sqm = sqb[mi];                      // uniform -> s_load
        int m = m0 + mi;
        float t1 = __fadd_rn(sqn, sqm);
        float d2 = __fsub_rn(t1, __fmul_rn(2.0f, a));
        float dist = __fsqrt_rn(fmaxf(d2, 0.f));
        u64 cand = ((u64)__float_as_uint(dist) << 32) | (u64)(u32)m;
        if ((m != n) && (cand < key[KNN - 1])) {
            bool placed = false;
#pragma unroll
            for (int j = KNN - 1; j >= 1; --j) {
                if (!placed) {
                    if (cand < key[j - 1]) {
                        key[j] = key[j - 1];
                    } else {
                        key[j] = cand;
                        placed = true;
                    }
                }
            }
            if (!placed) key[0] = cand;
        }
    }

    u64* dst = pKey + ((size_t)r * NCHUNK + c) * KNN;
#pragma unroll
    for (int j = 0; j < KNN; ++j) dst[j] = key[j];
}

// ---- kernel 2: merge 16 sorted partial lists per row, emit idx as float -
__global__ __launch_bounds__(256) void ef_knn_merge(const u64* __restrict__ pKey,
                                                    float* __restrict__ outIdxF) {
    int r = blockIdx.x * 256 + threadIdx.x;       // b*NPTS + n, 16384 rows
    const u64* src = pKey + (size_t)r * (NCHUNK * KNN);
    u64 key[KNN];
#pragma unroll
    for (int j = 0; j < KNN; ++j) key[j] = src[j];   // chunk 0 is sorted
    for (int c = 1; c < NCHUNK; ++c) {
#pragma unroll
        for (int j = 0; j < KNN; ++j) {
            u64 cand = src[c * KNN + j];
            if (cand < key[KNN - 1]) {
                bool placed = false;
#pragma unroll
                for (int p = KNN - 1; p >= 1; --p) {
                    if (!placed) {
                        if (cand < key[p - 1]) {
                            key[p] = key[p - 1];
                        } else {
                            key[p] = cand;
                            placed = true;
                        }
                    }
                }
                if (!placed) key[0] = cand;
            }
        }
    }
#pragma unroll
    for (int j = 0; j < KNN; ++j)
        outIdxF[(size_t)r * KNN + j] = (float)(u32)(key[j] & 0xFFFFFFFFu);
}

// ---- kernel 3: edge features -------------------------------------------
// out[b][ch][n][k]: ch<64 -> central, ch>=64 -> neighbor - central.
__global__ __launch_bounds__(256) void ef_edge_kernel(const float* __restrict__ pc,
                                                      const float* __restrict__ idxF,
                                                      float* __restrict__ out) {
    int gid = blockIdx.x * 256 + threadIdx.x;      // B*N*K = 262144
    int b = gid >> 16;                             // N*K = 65536
    int nk = gid & 65535;
    int n = nk >> 4;
    int m = (int)idxF[gid];
    const float* pcb = pc + (size_t)b * DIMS * NPTS;
    float* ob = out + (size_t)b * 2 * DIMS * NPTS * KNN;
#pragma unroll
    for (int d = 0; d < DIMS; ++d) {
        float cv = pcb[(size_t)d * NPTS + n];
        float nv = pcb[(size_t)d * NPTS + m];
        ob[(size_t)d * (NPTS * KNN) + nk] = cv;
        ob[(size_t)(DIMS + d) * (NPTS * KNN) + nk] = nv - cv;
    }
}

extern "C" void kernel_launch(void* const* d_in, const int* in_sizes, int n_in,
                              void* d_out, int out_size, void* d_ws, size_t ws_size,
                              hipStream_t stream) {
    const float* pc = (const float*)d_in[0];
    float* out = (float*)d_out;

    // Scratch inside the edge-feature region of d_out (fully overwritten by
    // ef_edge_kernel): pKey 33.5 MB ++ sq 64 KB ++ pcT 16 MB  (< 134 MB).
    u64* pKey = (u64*)d_out;                          // [B*N][NCHUNK][KNN] u64
    float* sq = out + 8388608;                        // 16384 floats
    float* pcT = out + 8388608 + 16384;               // 4,194,304 floats
    float* outIdxF = out + (size_t)BATCH * 2 * DIMS * NPTS * KNN; // 33,554,432

    ef_sq_kernel<<<(BATCH * NPTS) / 256, 256, 0, stream>>>(pc, sq);
    ef_transpose<<<dim3(NPTS / 64, BATCH), 256, 0, stream>>>(pc, pcT);
    ef_knn_partial<<<dim3((BATCH * NPTS) / 256, NCHUNK), 256, 0, stream>>>(pcT, sq, pKey);
    ef_knn_merge<<<(BATCH * NPTS) / 256, 256, 0, stream>>>(pKey, outIdxF);
    ef_edge_kernel<<<(BATCH * NPTS * KNN) / 256, 256, 0, stream>>>(pc, outIdxF, out);
}